// Round 1
// baseline (207.449 us; speedup 1.0000x reference)
//
#include <hip/hip_runtime.h>
#include <hip/hip_bf16.h>
#include <math.h>

#define B 8
#define H 256
#define W 256
#define HW (H * W)
#define BIGD 1e4f

// K1: boundary seed mask. f[idx] = 0.0 at boundary pixels, BIG elsewhere.
__global__ void k_boundary(const int* __restrict__ tgt, float* __restrict__ f) {
    int idx = blockIdx.x * 256 + threadIdx.x;   // < B*H*W
    int j = idx & (W - 1);
    int i = (idx >> 8) & (H - 1);
    bool tb = tgt[idx] != 0;
    bool er = false;
    if (i > 0 && i < H - 1 && j > 0 && j < W - 1) {
        er = true;
#pragma unroll
        for (int di = -1; di <= 1; ++di)
#pragma unroll
            for (int dj = -1; dj <= 1; ++dj)
                er = er && (tgt[idx + di * W + dj] != 0);
    }
    bool boundary = (tb != er);   // tb XOR erode
    f[idx] = boundary ? 0.0f : BIGD;
}

// K2: in-place vertical distance per column. One thread per (b, j).
// After down-scan, f==0 exactly at seeds, so the up-scan can re-detect seeds.
__global__ void k_vert(float* __restrict__ f) {
    int t = blockIdx.x * 256 + threadIdx.x;  // < B*W
    int j = t & (W - 1);
    int b = t >> 8;
    float* col = f + b * HW + j;
    float dd = BIGD;
    for (int i = 0; i < H; ++i) {
        float v = col[i * W];
        dd = (v == 0.0f) ? 0.0f : fminf(dd + 1.0f, BIGD);
        col[i * W] = dd;
    }
    float du = BIGD;
    for (int i = H - 1; i >= 0; --i) {
        float v = col[i * W];
        du = (v == 0.0f) ? 0.0f : fminf(du + 1.0f, BIGD);
        col[i * W] = fminf(v, du);
    }
}

// K3: exact EDT min-plus over columns. One block per (b,i) row.
__global__ void k_edt(const float* __restrict__ f, float* __restrict__ d) {
    __shared__ float f2[W];
    int row = blockIdx.x;      // b*H + i
    int t = threadIdx.x;       // j
    float v = f[row * W + t];
    f2[t] = v * v;
    __syncthreads();
    float m = 3.4e38f;
#pragma unroll 8
    for (int k = 0; k < W; ++k) {
        float dj = (float)(t - k);
        m = fminf(m, fmaf(dj, dj, f2[k]));   // broadcast LDS read, conflict-free
    }
    d[row * W + t] = sqrtf(m);
}

// K4: per-image max + sums in one pass; block per image.
__global__ void k_reduce(const float* __restrict__ logits,
                         const float* __restrict__ d,
                         float* __restrict__ per) {
    int b = blockIdx.x;
    int t = threadIdx.x;
    const float* db = d + b * HW;
    const float* lb = logits + b * HW;
    float mx = 0.0f, sd = 0.0f, spd = 0.0f;
    for (int k = t; k < HW; k += 256) {
        float dv = db[k];
        float lv = lb[k];
        float p = 1.0f / (1.0f + __expf(-lv));
        mx = fmaxf(mx, dv);
        sd += dv;
        spd += p * dv;
    }
    // wave (64) reduce, then cross-wave via LDS
    for (int o = 32; o > 0; o >>= 1) {
        mx  = fmaxf(mx, __shfl_down(mx, o));
        sd  += __shfl_down(sd, o);
        spd += __shfl_down(spd, o);
    }
    __shared__ float smx[4], ssd[4], sspd[4];
    int lane = t & 63, w = t >> 6;
    if (lane == 0) { smx[w] = mx; ssd[w] = sd; sspd[w] = spd; }
    __syncthreads();
    if (t == 0) {
        mx = smx[0]; sd = ssd[0]; spd = sspd[0];
        for (int ww = 1; ww < 4; ++ww) {
            mx = fmaxf(mx, smx[ww]); sd += ssd[ww]; spd += sspd[ww];
        }
        float M = mx + 1e-7f;
        per[b] = (spd / M) / (sd / M + 1e-7f);
    }
}

// K5: mean over batch.
__global__ void k_final(const float* __restrict__ per, float* __restrict__ out) {
    if (threadIdx.x == 0) {
        float s = 0.0f;
        for (int b = 0; b < B; ++b) s += per[b];
        out[0] = s * (1.0f / (float)B);
    }
}

extern "C" void kernel_launch(void* const* d_in, const int* in_sizes, int n_in,
                              void* d_out, int out_size, void* d_ws, size_t ws_size,
                              hipStream_t stream) {
    const float* logits = (const float*)d_in[0];
    const int*   target = (const int*)d_in[1];
    float* out = (float*)d_out;

    float* f   = (float*)d_ws;          // B*H*W floats
    float* d   = f + B * HW;            // B*H*W floats
    float* per = d + B * HW;            // B floats

    k_boundary<<<B * HW / 256, 256, 0, stream>>>(target, f);
    k_vert<<<B * W / 256, 256, 0, stream>>>(f);
    k_edt<<<B * H, 256, 0, stream>>>(f, d);
    k_reduce<<<B, 256, 0, stream>>>(logits, d, per);
    k_final<<<1, 64, 0, stream>>>(per, out);
}

// Round 2
// 119.717 us; speedup vs baseline: 1.7328x; 1.7328x over previous
//
#include <hip/hip_runtime.h>
#include <hip/hip_bf16.h>
#include <math.h>

#define B 8
#define H 256
#define W 256
#define HW (H * W)
#define BIGD 1e4f
#define NEGBIG (-1e9f)

// K1: boundary seed mask. f[idx] = 0.0 at boundary pixels, BIG elsewhere.
__global__ void k_boundary(const int* __restrict__ tgt, float* __restrict__ f) {
    int idx = blockIdx.x * 256 + threadIdx.x;   // < B*H*W
    int j = idx & (W - 1);
    int i = (idx >> 8) & (H - 1);
    bool tb = tgt[idx] != 0;
    bool er = false;
    if (i > 0 && i < H - 1 && j > 0 && j < W - 1) {
        er = true;
#pragma unroll
        for (int di = -1; di <= 1; ++di)
#pragma unroll
            for (int dj = -1; dj <= 1; ++dj)
                er = er && (tgt[idx + di * W + dj] != 0);
    }
    bool boundary = (tb != er);   // tb XOR erode
    f[idx] = boundary ? 0.0f : BIGD;
}

// K2: vertical distance per column via wave-parallel cummax scan.
// One wave (64 lanes) per column, lane l owns rows 4l..4l+3.
// Writes f^2 (squared vertical distance, capped at BIGD^2... capped at BIGD then squared).
__global__ void k_vert(float* __restrict__ f) {
    int lane = threadIdx.x & 63;
    int col  = blockIdx.x * 4 + (threadIdx.x >> 6);   // < B*W
    int b = col >> 8, j = col & (W - 1);
    float* base = f + b * HW + j;

    float v[4];
#pragma unroll
    for (int k = 0; k < 4; ++k) v[k] = base[(lane * 4 + k) * W];

    // ---- down-scan: nearest seed index at-or-above (inclusive cummax) ----
    float s[4];
#pragma unroll
    for (int k = 0; k < 4; ++k)
        s[k] = (v[k] == 0.0f) ? (float)(lane * 4 + k) : NEGBIG;
    s[1] = fmaxf(s[1], s[0]); s[2] = fmaxf(s[2], s[1]); s[3] = fmaxf(s[3], s[2]);
    float inc = s[3];
#pragma unroll
    for (int off = 1; off < 64; off <<= 1) {
        float u = __shfl_up(inc, off);
        if (lane >= off) inc = fmaxf(inc, u);
    }
    float ex = __shfl_up(inc, 1);
    if (lane == 0) ex = NEGBIG;
    float down[4];
#pragma unroll
    for (int k = 0; k < 4; ++k)
        down[k] = (float)(lane * 4 + k) - fmaxf(s[k], ex);

    // ---- up-scan: nearest seed index at-or-below (suffix cummax) ----
    float su[4];
#pragma unroll
    for (int k = 0; k < 4; ++k)
        su[k] = (v[k] == 0.0f) ? (float)(H - 1 - (lane * 4 + k)) : NEGBIG;
    su[2] = fmaxf(su[2], su[3]); su[1] = fmaxf(su[1], su[2]); su[0] = fmaxf(su[0], su[1]);
    float incu = su[0];
#pragma unroll
    for (int off = 1; off < 64; off <<= 1) {
        float u = __shfl_down(incu, off);
        if (lane < 64 - off) incu = fmaxf(incu, u);
    }
    float exu = __shfl_down(incu, 1);
    if (lane == 63) exu = NEGBIG;

#pragma unroll
    for (int k = 0; k < 4; ++k) {
        float up = (float)(H - 1 - (lane * 4 + k)) - fmaxf(su[k], exu);
        float fv = fminf(fminf(down[k], up), BIGD);
        base[(lane * 4 + k) * W] = fv * fv;   // store squared
    }
}

// K3: exact EDT min-plus over columns, fused with per-row partial reduction.
// One block per (b,i) row. rowpart[row] = {max d, sum d, sum p*d, pad}.
__global__ void k_edt_reduce(const float* __restrict__ f2in,
                             const float* __restrict__ logits,
                             float* __restrict__ rowpart) {
    __shared__ float f2[W];
    int row = blockIdx.x;      // b*H + i
    int t = threadIdx.x;       // j
    f2[t] = f2in[row * W + t];
    __syncthreads();
    float m = 3.4e38f;
#pragma unroll 8
    for (int k = 0; k < W; ++k) {
        float dj = (float)(t - k);
        m = fminf(m, fmaf(dj, dj, f2[k]));   // broadcast LDS read, conflict-free
    }
    float d = sqrtf(m);
    float lv = logits[row * W + t];
    float p = 1.0f / (1.0f + __expf(-lv));
    float pd = p * d;

    float mx = d, sd = d, spd = pd;
#pragma unroll
    for (int o = 32; o > 0; o >>= 1) {
        mx  = fmaxf(mx, __shfl_down(mx, o));
        sd  += __shfl_down(sd, o);
        spd += __shfl_down(spd, o);
    }
    __shared__ float sm[4][3];
    int lane = t & 63, w = t >> 6;
    if (lane == 0) { sm[w][0] = mx; sm[w][1] = sd; sm[w][2] = spd; }
    __syncthreads();
    if (t == 0) {
        for (int ww = 1; ww < 4; ++ww) {
            sm[0][0] = fmaxf(sm[0][0], sm[ww][0]);
            sm[0][1] += sm[ww][1];
            sm[0][2] += sm[ww][2];
        }
        rowpart[row * 4 + 0] = sm[0][0];
        rowpart[row * 4 + 1] = sm[0][1];
        rowpart[row * 4 + 2] = sm[0][2];
    }
}

// K4: single block combines 2048 row partials -> per-image loss -> mean.
__global__ void k_final(const float* __restrict__ rowpart, float* __restrict__ out) {
    int t = threadIdx.x;   // 256 threads, thread t handles row i=t of each image
    __shared__ float sm[4][3];
    float total = 0.0f;
    for (int b = 0; b < B; ++b) {
        float mx  = rowpart[(b * H + t) * 4 + 0];
        float sd  = rowpart[(b * H + t) * 4 + 1];
        float spd = rowpart[(b * H + t) * 4 + 2];
#pragma unroll
        for (int o = 32; o > 0; o >>= 1) {
            mx  = fmaxf(mx, __shfl_down(mx, o));
            sd  += __shfl_down(sd, o);
            spd += __shfl_down(spd, o);
        }
        int lane = t & 63, w = t >> 6;
        if (lane == 0) { sm[w][0] = mx; sm[w][1] = sd; sm[w][2] = spd; }
        __syncthreads();
        if (t == 0) {
            for (int ww = 1; ww < 4; ++ww) {
                sm[0][0] = fmaxf(sm[0][0], sm[ww][0]);
                sm[0][1] += sm[ww][1];
                sm[0][2] += sm[ww][2];
            }
            float M = sm[0][0] + 1e-7f;
            total += (sm[0][2] / M) / (sm[0][1] / M + 1e-7f);
        }
        __syncthreads();
    }
    if (t == 0) out[0] = total * (1.0f / (float)B);
}

extern "C" void kernel_launch(void* const* d_in, const int* in_sizes, int n_in,
                              void* d_out, int out_size, void* d_ws, size_t ws_size,
                              hipStream_t stream) {
    const float* logits = (const float*)d_in[0];
    const int*   target = (const int*)d_in[1];
    float* out = (float*)d_out;

    float* f       = (float*)d_ws;        // B*H*W floats (2 MB)
    float* rowpart = f + B * HW;          // B*H*4 floats (32 KB)

    k_boundary<<<B * HW / 256, 256, 0, stream>>>(target, f);
    k_vert<<<B * W / 4, 256, 0, stream>>>(f);
    k_edt_reduce<<<B * H, 256, 0, stream>>>(f, logits, rowpart);
    k_final<<<1, 256, 0, stream>>>(rowpart, out);
}